// Round 4
// baseline (107.945 us; speedup 1.0000x reference)
//
#include <hip/hip_runtime.h>
#include <hip/hip_bf16.h>

// Problem constants
#define NS    65536
#define KEXP  8
#define WID   64
#define DOUT  32
#define DIN   74
#define TM    64     // samples per tile
#define XS    104    // X row stride (u16 elems), mult of 8 for 16B-aligned b128 frags
#define HS    72     // H / W1t / W2t row stride (u16)
#define OSF   36     // out-staging row stride (f32), 144B = 16B-aligned rows
#define GX    64     // blocks per expert in MLP kernel
#define HDR   32768  // int-offset of header within ws (after 65536 u16 bucket)

typedef __attribute__((ext_vector_type(8))) short short8;
typedef __attribute__((ext_vector_type(4))) float floatx4;

// f32 -> bf16 with round-to-nearest-even (truncation would double our error).
__device__ __forceinline__ unsigned short f2b(float f) {
  unsigned u = __builtin_bit_cast(unsigned, f);
  u = u + 0x7FFFu + ((u >> 16) & 1u);
  return (unsigned short)(u >> 16);
}

// d_ws layout:
//   bytes [0 .. 131072)        : bucket, 65536 x u16 sample ids grouped by expert
//   ints  [HDR+0  .. HDR+8)    : cnt per expert
//   ints  [HDR+8  .. HDR+16)   : seg offsets (exclusive scan)
//   ints  [HDR+16 .. HDR+24)   : scatter cursors
// total 131,168 bytes.

__global__ void k_zero(int* __restrict__ hdr) {
  if (threadIdx.x < KEXP) hdr[threadIdx.x] = 0;
}

__global__ __launch_bounds__(256) void k_count(const int* __restrict__ idxs,
                                               int* __restrict__ hdr) {
  __shared__ int lc[KEXP];
  const int tid = threadIdx.x;
  if (tid < KEXP) lc[tid] = 0;
  __syncthreads();
  const int e = idxs[blockIdx.x * 256 + tid];
  atomicAdd(&lc[e], 1);
  __syncthreads();
  if (tid < KEXP) atomicAdd(&hdr[tid], lc[tid]);
}

__global__ void k_scan(int* __restrict__ hdr) {
  if (threadIdx.x == 0) {
    int acc = 0;
    for (int e = 0; e < KEXP; ++e) {
      hdr[8 + e] = acc;
      hdr[16 + e] = acc;
      acc += hdr[e];
    }
  }
}

__global__ __launch_bounds__(256) void k_scatter(const int* __restrict__ idxs,
                                                 int* __restrict__ hdr,
                                                 unsigned short* __restrict__ bucket) {
  __shared__ int lc[KEXP];
  __shared__ int lbase[KEXP];
  const int tid = threadIdx.x;
  if (tid < KEXP) lc[tid] = 0;
  __syncthreads();
  const int gid = blockIdx.x * 256 + tid;
  const int e = idxs[gid];
  const int rank = atomicAdd(&lc[e], 1);
  __syncthreads();
  if (tid < KEXP) lbase[tid] = atomicAdd(&hdr[16 + tid], lc[tid]);
  __syncthreads();
  bucket[lbase[e] + rank] = (unsigned short)gid;
}

__global__ __launch_bounds__(256) void k_mlp(
    const int* __restrict__ hdr,
    const unsigned short* __restrict__ bucket,
    const float* __restrict__ pos,
    const float* __restrict__ view,
    const float* __restrict__ feat,
    const float* __restrict__ W0,
    const float* __restrict__ B0,
    const float* __restrict__ W1,
    const float* __restrict__ B1,
    const float* __restrict__ W2,
    const float* __restrict__ B2,
    float* __restrict__ out)
{
  const int e = blockIdx.y;
  const int segCnt = hdr[e];
  if ((int)blockIdx.x * TM >= segCnt) return;
  const int segStart = hdr[8 + e];
  const int tid = threadIdx.x;

  __shared__ __align__(16) unsigned short Xs[TM * XS];
  __shared__ __align__(16) unsigned short W0t[WID * XS];
  __shared__ __align__(16) unsigned short W1t[WID * HS];
  __shared__ __align__(16) unsigned short W2t[DOUT * HS];
  __shared__ __align__(16) unsigned short Hs[TM * HS];
  __shared__ __align__(16) float Os[TM * OSF];
  __shared__ float sb0[WID];
  __shared__ float sb1[WID];
  __shared__ float sb2[DOUT];
  __shared__ int sid[TM];

  // Zero X (k-padding 74..95 must be 0) and W0t (same padding).
  for (int i = tid; i < TM * XS; i += 256) Xs[i] = 0;
  for (int i = tid; i < WID * XS; i += 256) W0t[i] = 0;
  __syncthreads();

  // Stage this expert's weights transposed (f32 -> bf16): Wt[o][i] = W[i][o].
  {
    const float* g0 = W0 + (size_t)e * DIN * WID;
    for (int g = tid; g < DIN * WID; g += 256) {
      int i = g >> 6, o = g & 63;
      W0t[o * XS + i] = f2b(g0[g]);
    }
    const float* g1 = W1 + (size_t)e * WID * WID;
    for (int g = tid; g < WID * WID; g += 256) {
      int i = g >> 6, o = g & 63;
      W1t[o * HS + i] = f2b(g1[g]);
    }
    const float* g2 = W2 + (size_t)e * WID * DOUT;
    for (int g = tid; g < WID * DOUT; g += 256) {
      int i = g >> 5, o = g & 31;
      W2t[o * HS + i] = f2b(g2[g]);
    }
    if (tid < WID) {
      sb0[tid] = B0[e * WID + tid];
      sb1[tid] = B1[e * WID + tid];
    } else if (tid < WID + DOUT) {
      int t = tid - WID;
      sb2[t] = B2[e * DOUT + t];
    }
  }
  __syncthreads();

  const int lane = tid & 63;
  const int wv = tid >> 6;
  const int quad = lane >> 4;
  const int r16 = lane & 15;
  const int rb = wv * 16;

  for (int tile = blockIdx.x; tile * TM < segCnt; tile += GX) {
    const int t0 = tile * TM;
    const int rows = min(TM, segCnt - t0);

    // ---- build X tile: row = lane, 4-way split across waves ----
    const int r = lane;
    if (r < rows) {
      const int s = (int)bucket[segStart + t0 + r];
      unsigned short* xr = &Xs[r * XS];
      if (wv == 0) {
        sid[r] = s;
        const float4* fs = (const float4*)(feat + (size_t)s * DOUT);
        #pragma unroll
        for (int q = 0; q < 4; ++q) {
          float4 f = fs[q];
          xr[q * 4 + 0] = f2b(f.x);
          xr[q * 4 + 1] = f2b(f.y);
          xr[q * 4 + 2] = f2b(f.z);
          xr[q * 4 + 3] = f2b(f.w);
        }
      } else if (wv == 1) {
        const float4* fs = (const float4*)(feat + (size_t)s * DOUT);
        #pragma unroll
        for (int q = 4; q < 8; ++q) {
          float4 f = fs[q];
          xr[q * 4 + 0] = f2b(f.x);
          xr[q * 4 + 1] = f2b(f.y);
          xr[q * 4 + 2] = f2b(f.z);
          xr[q * 4 + 3] = f2b(f.w);
        }
      } else if (wv == 2) {
        // posenc(positions, deg=2): cols 32..46
        float p[3];
        p[0] = pos[s * 3 + 0];
        p[1] = pos[s * 3 + 1];
        p[2] = pos[s * 3 + 2];
        #pragma unroll
        for (int d = 0; d < 3; ++d) xr[32 + d] = f2b(p[d]);
        #pragma unroll
        for (int si = 0; si < 2; ++si) {
          const float sc = (float)(1 << si);
          #pragma unroll
          for (int d = 0; d < 3; ++d) {
            const float a = p[d] * sc;
            xr[35 + si * 3 + d] = f2b(__sinf(a));
            xr[41 + si * 3 + d] = f2b(__cosf(a));
          }
        }
      } else {
        // posenc(viewdirs, deg=4): cols 47..73
        float v[3];
        v[0] = view[s * 3 + 0];
        v[1] = view[s * 3 + 1];
        v[2] = view[s * 3 + 2];
        #pragma unroll
        for (int d = 0; d < 3; ++d) xr[47 + d] = f2b(v[d]);
        #pragma unroll
        for (int si = 0; si < 4; ++si) {
          const float sc = (float)(1 << si);
          #pragma unroll
          for (int d = 0; d < 3; ++d) {
            const float a = v[d] * sc;
            xr[50 + si * 3 + d] = f2b(__sinf(a));
            xr[62 + si * 3 + d] = f2b(__cosf(a));
          }
        }
      }
    }
    __syncthreads();

    // ---- layer 0: [64 x 96] @ [96 x 64] -> H (relu) ----
    {
      const short8 a0 = *(const short8*)&Xs[(rb + r16) * XS + 0 + quad * 8];
      const short8 a1 = *(const short8*)&Xs[(rb + r16) * XS + 32 + quad * 8];
      const short8 a2 = *(const short8*)&Xs[(rb + r16) * XS + 64 + quad * 8];
      #pragma unroll
      for (int c = 0; c < 4; ++c) {
        const int n0 = c * 16;
        floatx4 acc = {0.f, 0.f, 0.f, 0.f};
        acc = __builtin_amdgcn_mfma_f32_16x16x32_bf16(
            a0, *(const short8*)&W0t[(n0 + r16) * XS + 0 + quad * 8], acc, 0, 0, 0);
        acc = __builtin_amdgcn_mfma_f32_16x16x32_bf16(
            a1, *(const short8*)&W0t[(n0 + r16) * XS + 32 + quad * 8], acc, 0, 0, 0);
        acc = __builtin_amdgcn_mfma_f32_16x16x32_bf16(
            a2, *(const short8*)&W0t[(n0 + r16) * XS + 64 + quad * 8], acc, 0, 0, 0);
        const float bias = sb0[n0 + r16];
        #pragma unroll
        for (int g = 0; g < 4; ++g) {
          const float vv = fmaxf(acc[g] + bias, 0.f);
          Hs[(rb + quad * 4 + g) * HS + n0 + r16] = f2b(vv);
        }
      }
    }
    __syncthreads();

    // ---- layer 1: [64 x 64] @ [64 x 64] -> H (relu, wave-local rows) ----
    {
      const short8 h0 = *(const short8*)&Hs[(rb + r16) * HS + 0 + quad * 8];
      const short8 h1 = *(const short8*)&Hs[(rb + r16) * HS + 32 + quad * 8];
      __syncthreads();   // h0/h1 in regs; Hs rewritten below
      #pragma unroll
      for (int c = 0; c < 4; ++c) {
        const int n0 = c * 16;
        floatx4 acc = {0.f, 0.f, 0.f, 0.f};
        acc = __builtin_amdgcn_mfma_f32_16x16x32_bf16(
            h0, *(const short8*)&W1t[(n0 + r16) * HS + 0 + quad * 8], acc, 0, 0, 0);
        acc = __builtin_amdgcn_mfma_f32_16x16x32_bf16(
            h1, *(const short8*)&W1t[(n0 + r16) * HS + 32 + quad * 8], acc, 0, 0, 0);
        const float bias = sb1[n0 + r16];
        #pragma unroll
        for (int g = 0; g < 4; ++g) {
          const float vv = fmaxf(acc[g] + bias, 0.f);
          Hs[(rb + quad * 4 + g) * HS + n0 + r16] = f2b(vv);
        }
      }
    }
    __syncthreads();

    // ---- layer 2: [64 x 64] @ [64 x 32] -> Os (no relu, f32 out) ----
    {
      const short8 q0 = *(const short8*)&Hs[(rb + r16) * HS + 0 + quad * 8];
      const short8 q1 = *(const short8*)&Hs[(rb + r16) * HS + 32 + quad * 8];
      #pragma unroll
      for (int c = 0; c < 2; ++c) {
        const int n0 = c * 16;
        floatx4 acc = {0.f, 0.f, 0.f, 0.f};
        acc = __builtin_amdgcn_mfma_f32_16x16x32_bf16(
            q0, *(const short8*)&W2t[(n0 + r16) * HS + 0 + quad * 8], acc, 0, 0, 0);
        acc = __builtin_amdgcn_mfma_f32_16x16x32_bf16(
            q1, *(const short8*)&W2t[(n0 + r16) * HS + 32 + quad * 8], acc, 0, 0, 0);
        const float bias = sb2[n0 + r16];
        #pragma unroll
        for (int g = 0; g < 4; ++g) {
          Os[(rb + quad * 4 + g) * OSF + n0 + r16] = acc[g] + bias;
        }
      }
    }
    __syncthreads();

    // ---- scatter rows to output (f32, 128B per row) ----
    if (tid < rows) {
      const int s = sid[tid];
      float4* dst = (float4*)(out + (size_t)s * DOUT);
      const float4* src = (const float4*)&Os[tid * OSF];
      #pragma unroll
      for (int q = 0; q < 8; ++q) dst[q] = src[q];
    }
    __syncthreads();
  }
}

extern "C" void kernel_launch(void* const* d_in, const int* in_sizes, int n_in,
                              void* d_out, int out_size, void* d_ws, size_t ws_size,
                              hipStream_t stream) {
  const int* idxs        = (const int*)d_in[0];
  const float* pos       = (const float*)d_in[1];
  const float* view      = (const float*)d_in[2];
  const float* feat      = (const float*)d_in[3];
  const float* W0        = (const float*)d_in[4];
  const float* b0        = (const float*)d_in[5];
  const float* W1        = (const float*)d_in[6];
  const float* b1        = (const float*)d_in[7];
  const float* W2        = (const float*)d_in[8];
  const float* b2        = (const float*)d_in[9];
  float* out             = (float*)d_out;
  unsigned short* bucket = (unsigned short*)d_ws;
  int* hdr               = (int*)d_ws + HDR;

  k_zero<<<1, 64, 0, stream>>>(hdr);
  k_count<<<NS / 256, 256, 0, stream>>>(idxs, hdr);
  k_scan<<<1, 64, 0, stream>>>(hdr);
  k_scatter<<<NS / 256, 256, 0, stream>>>(idxs, hdr, bucket);
  dim3 grid(GX, KEXP);
  k_mlp<<<grid, 256, 0, stream>>>(hdr, bucket, pos, view, feat,
                                  W0, b0, W1, b1, W2, b2, out);
}

// Round 5
// 103.984 us; speedup vs baseline: 1.0381x; 1.0381x over previous
//
#include <hip/hip_runtime.h>
#include <hip/hip_bf16.h>

// Problem constants
#define NS    65536
#define KEXP  8
#define WID   64
#define DOUT  32
#define DIN   74
#define TM    64     // samples per tile
#define XS    104    // X row stride (u16), mult of 8 -> 16B-aligned b128 frags
#define HS    72     // H / W1t / W2t row stride (u16)
#define GX    64     // blocks per expert in MLP kernel
#define SEGCAP 65536 // fixed per-expert bucket capacity

typedef __attribute__((ext_vector_type(8))) short short8;
typedef __attribute__((ext_vector_type(4))) float floatx4;

// f32 -> bf16 round-to-nearest-even.
__device__ __forceinline__ unsigned short f2b(float f) {
  unsigned u = __builtin_bit_cast(unsigned, f);
  u = u + 0x7FFFu + ((u >> 16) & 1u);
  return (unsigned short)(u >> 16);
}

// d_ws layout:
//   bytes [0 .. 1MB)      : bucket, u16[KEXP][SEGCAP], ids grouped by expert
//   bytes [1MB .. 1MB+32) : cursors, int[8] (per-expert counts, atomically built)
// ws_size is ~256MB; we use ~1MB.

__global__ __launch_bounds__(256) void k_scatter(const int* __restrict__ idxs,
                                                 int* __restrict__ cursors,
                                                 unsigned short* __restrict__ bucket) {
  __shared__ int lc[KEXP];
  __shared__ int lbase[KEXP];
  const int tid = threadIdx.x;
  if (tid < KEXP) lc[tid] = 0;
  __syncthreads();
  const int gid = blockIdx.x * 256 + tid;
  const int e = idxs[gid];
  const int rank = atomicAdd(&lc[e], 1);
  __syncthreads();
  if (tid < KEXP) lbase[tid] = atomicAdd(&cursors[tid], lc[tid]);
  __syncthreads();
  bucket[(e << 16) + lbase[e] + rank] = (unsigned short)gid;
}

__global__ __launch_bounds__(256) void k_mlp(
    const int* __restrict__ cursors,
    const unsigned short* __restrict__ bucket,
    const float* __restrict__ pos,
    const float* __restrict__ view,
    const float* __restrict__ feat,
    const float* __restrict__ W0,
    const float* __restrict__ B0,
    const float* __restrict__ W1,
    const float* __restrict__ B1,
    const float* __restrict__ W2,
    const float* __restrict__ B2,
    float* __restrict__ out)
{
  const int e = blockIdx.y;
  const int segCnt = cursors[e];
  if ((int)blockIdx.x * TM >= segCnt) return;
  const int segStart = e << 16;
  const int tid = threadIdx.x;

  __shared__ __align__(16) unsigned short Xs[TM * XS];
  __shared__ __align__(16) unsigned short W0t[WID * XS];
  __shared__ __align__(16) unsigned short W1t[WID * HS];
  __shared__ __align__(16) unsigned short W2t[DOUT * HS];
  __shared__ __align__(16) unsigned short Hs[TM * HS];
  __shared__ float sb0[WID];
  __shared__ float sb1[WID];
  __shared__ float sb2[DOUT];
  __shared__ int sid[TM];

  // Zero Xs k-padding region (cols 74..95 read by MFMA) and W0t padding.
  for (int i = tid; i < TM * XS; i += 256) Xs[i] = 0;
  for (int i = tid; i < WID * XS; i += 256) W0t[i] = 0;
  __syncthreads();

  // ---- stage weights transposed, Wt[o][i] = W[i][o], 4 i per thread ----
  // Reads are coalesced along o (row-major rows); writes are packed b64.
  {
    const float* g0 = W0 + (size_t)e * DIN * WID;
    for (int g = tid; g < 19 * WID; g += 256) {        // ceil(74/4)=19 blocks
      const int o = g & 63, i4 = g >> 6, ib = i4 * 4;
      unsigned v0 = 0, v1 = 0;
      #pragma unroll
      for (int j = 0; j < 4; ++j) {
        const int i = ib + j;
        unsigned short w = (i < DIN) ? f2b(g0[i * WID + o]) : (unsigned short)0;
        if (j < 2) v0 |= (unsigned)w << (16 * j);
        else       v1 |= (unsigned)w << (16 * (j - 2));
      }
      *(uint2*)&W0t[o * XS + ib] = make_uint2(v0, v1);
    }
    const float* g1 = W1 + (size_t)e * WID * WID;
    for (int g = tid; g < 16 * WID; g += 256) {
      const int o = g & 63, i4 = g >> 6, ib = i4 * 4;
      unsigned v0, v1;
      v0 = (unsigned)f2b(g1[(ib + 0) * WID + o]) | ((unsigned)f2b(g1[(ib + 1) * WID + o]) << 16);
      v1 = (unsigned)f2b(g1[(ib + 2) * WID + o]) | ((unsigned)f2b(g1[(ib + 3) * WID + o]) << 16);
      *(uint2*)&W1t[o * HS + ib] = make_uint2(v0, v1);
    }
    const float* g2 = W2 + (size_t)e * WID * DOUT;
    for (int g = tid; g < 16 * DOUT; g += 256) {
      const int o = g & 31, i4 = g >> 5, ib = i4 * 4;
      unsigned v0, v1;
      v0 = (unsigned)f2b(g2[(ib + 0) * DOUT + o]) | ((unsigned)f2b(g2[(ib + 1) * DOUT + o]) << 16);
      v1 = (unsigned)f2b(g2[(ib + 2) * DOUT + o]) | ((unsigned)f2b(g2[(ib + 3) * DOUT + o]) << 16);
      *(uint2*)&W2t[o * HS + ib] = make_uint2(v0, v1);
    }
    if (tid < WID) {
      sb0[tid] = B0[e * WID + tid];
      sb1[tid] = B1[e * WID + tid];
    } else if (tid < WID + DOUT) {
      const int t = tid - WID;
      sb2[t] = B2[e * DOUT + t];
    }
  }
  __syncthreads();

  const int lane = tid & 63;
  const int wv = tid >> 6;
  const int quad = lane >> 4;
  const int r16 = lane & 15;
  const int rb = wv * 16;

  for (int tile = blockIdx.x; tile * TM < segCnt; tile += GX) {
    const int t0 = tile * TM;
    const int rows = min(TM, segCnt - t0);

    __syncthreads();   // protect Xs/sid rebuild vs previous iteration's readers

    // ---- build X tile: row = lane, 4-way split across waves ----
    const int r = lane;
    if (r < rows) {
      const int s = (int)bucket[segStart + t0 + r];
      unsigned short* xr = &Xs[r * XS];
      if (wv == 0) {
        sid[r] = s;
        const float4* fs = (const float4*)(feat + (size_t)s * DOUT);
        #pragma unroll
        for (int q = 0; q < 4; ++q) {
          float4 f = fs[q];
          xr[q * 4 + 0] = f2b(f.x);
          xr[q * 4 + 1] = f2b(f.y);
          xr[q * 4 + 2] = f2b(f.z);
          xr[q * 4 + 3] = f2b(f.w);
        }
      } else if (wv == 1) {
        const float4* fs = (const float4*)(feat + (size_t)s * DOUT);
        #pragma unroll
        for (int q = 4; q < 8; ++q) {
          float4 f = fs[q];
          xr[q * 4 + 0] = f2b(f.x);
          xr[q * 4 + 1] = f2b(f.y);
          xr[q * 4 + 2] = f2b(f.z);
          xr[q * 4 + 3] = f2b(f.w);
        }
      } else if (wv == 2) {
        // posenc(positions, deg=2): cols 32..46
        float p[3];
        p[0] = pos[s * 3 + 0];
        p[1] = pos[s * 3 + 1];
        p[2] = pos[s * 3 + 2];
        #pragma unroll
        for (int d = 0; d < 3; ++d) xr[32 + d] = f2b(p[d]);
        #pragma unroll
        for (int si = 0; si < 2; ++si) {
          const float sc = (float)(1 << si);
          #pragma unroll
          for (int d = 0; d < 3; ++d) {
            const float a = p[d] * sc;
            xr[35 + si * 3 + d] = f2b(__sinf(a));
            xr[41 + si * 3 + d] = f2b(__cosf(a));
          }
        }
      } else {
        // posenc(viewdirs, deg=4): cols 47..73
        float v[3];
        v[0] = view[s * 3 + 0];
        v[1] = view[s * 3 + 1];
        v[2] = view[s * 3 + 2];
        #pragma unroll
        for (int d = 0; d < 3; ++d) xr[47 + d] = f2b(v[d]);
        #pragma unroll
        for (int si = 0; si < 4; ++si) {
          const float sc = (float)(1 << si);
          #pragma unroll
          for (int d = 0; d < 3; ++d) {
            const float a = v[d] * sc;
            xr[50 + si * 3 + d] = f2b(__sinf(a));
            xr[62 + si * 3 + d] = f2b(__cosf(a));
          }
        }
      }
    }
    __syncthreads();

    // ---- layer 0: [64 x 96] @ [96 x 64] -> Hs (relu). Hs rows are wave-private
    //      from here on: no cross-wave barriers needed until next X rebuild. ----
    {
      const short8 a0 = *(const short8*)&Xs[(rb + r16) * XS + 0 + quad * 8];
      const short8 a1 = *(const short8*)&Xs[(rb + r16) * XS + 32 + quad * 8];
      const short8 a2 = *(const short8*)&Xs[(rb + r16) * XS + 64 + quad * 8];
      #pragma unroll
      for (int c = 0; c < 4; ++c) {
        const int n0 = c * 16;
        floatx4 acc = {0.f, 0.f, 0.f, 0.f};
        acc = __builtin_amdgcn_mfma_f32_16x16x32_bf16(
            a0, *(const short8*)&W0t[(n0 + r16) * XS + 0 + quad * 8], acc, 0, 0, 0);
        acc = __builtin_amdgcn_mfma_f32_16x16x32_bf16(
            a1, *(const short8*)&W0t[(n0 + r16) * XS + 32 + quad * 8], acc, 0, 0, 0);
        acc = __builtin_amdgcn_mfma_f32_16x16x32_bf16(
            a2, *(const short8*)&W0t[(n0 + r16) * XS + 64 + quad * 8], acc, 0, 0, 0);
        const float bias = sb0[n0 + r16];
        #pragma unroll
        for (int g = 0; g < 4; ++g) {
          const float vv = fmaxf(acc[g] + bias, 0.f);
          Hs[(rb + quad * 4 + g) * HS + n0 + r16] = f2b(vv);
        }
      }
    }

    // ---- layer 1: [64 x 64] @ [64 x 64] -> Hs (relu, wave-private rows) ----
    {
      const short8 h0 = *(const short8*)&Hs[(rb + r16) * HS + 0 + quad * 8];
      const short8 h1 = *(const short8*)&Hs[(rb + r16) * HS + 32 + quad * 8];
      #pragma unroll
      for (int c = 0; c < 4; ++c) {
        const int n0 = c * 16;
        floatx4 acc = {0.f, 0.f, 0.f, 0.f};
        acc = __builtin_amdgcn_mfma_f32_16x16x32_bf16(
            h0, *(const short8*)&W1t[(n0 + r16) * HS + 0 + quad * 8], acc, 0, 0, 0);
        acc = __builtin_amdgcn_mfma_f32_16x16x32_bf16(
            h1, *(const short8*)&W1t[(n0 + r16) * HS + 32 + quad * 8], acc, 0, 0, 0);
        const float bias = sb1[n0 + r16];
        #pragma unroll
        for (int g = 0; g < 4; ++g) {
          const float vv = fmaxf(acc[g] + bias, 0.f);
          Hs[(rb + quad * 4 + g) * HS + n0 + r16] = f2b(vv);
        }
      }
    }

    // ---- layer 2: [64 x 64] @ [64 x 32] -> direct f32 global stores ----
    {
      const short8 q0 = *(const short8*)&Hs[(rb + r16) * HS + 0 + quad * 8];
      const short8 q1 = *(const short8*)&Hs[(rb + r16) * HS + 32 + quad * 8];
      #pragma unroll
      for (int c = 0; c < 2; ++c) {
        const int n0 = c * 16;
        floatx4 acc = {0.f, 0.f, 0.f, 0.f};
        acc = __builtin_amdgcn_mfma_f32_16x16x32_bf16(
            q0, *(const short8*)&W2t[(n0 + r16) * HS + 0 + quad * 8], acc, 0, 0, 0);
        acc = __builtin_amdgcn_mfma_f32_16x16x32_bf16(
            q1, *(const short8*)&W2t[(n0 + r16) * HS + 32 + quad * 8], acc, 0, 0, 0);
        const float bias = sb2[n0 + r16];
        const int col = n0 + r16;
        #pragma unroll
        for (int g = 0; g < 4; ++g) {
          const int row = rb + quad * 4 + g;
          if (row < rows) {
            out[(size_t)sid[row] * DOUT + col] = acc[g] + bias;
          }
        }
      }
    }
  }
}

extern "C" void kernel_launch(void* const* d_in, const int* in_sizes, int n_in,
                              void* d_out, int out_size, void* d_ws, size_t ws_size,
                              hipStream_t stream) {
  const int* idxs        = (const int*)d_in[0];
  const float* pos       = (const float*)d_in[1];
  const float* view      = (const float*)d_in[2];
  const float* feat      = (const float*)d_in[3];
  const float* W0        = (const float*)d_in[4];
  const float* b0        = (const float*)d_in[5];
  const float* W1        = (const float*)d_in[6];
  const float* b1        = (const float*)d_in[7];
  const float* W2        = (const float*)d_in[8];
  const float* b2        = (const float*)d_in[9];
  float* out             = (float*)d_out;
  unsigned short* bucket = (unsigned short*)d_ws;
  int* cursors           = (int*)((char*)d_ws + (size_t)KEXP * SEGCAP * 2);

  hipMemsetAsync(cursors, 0, KEXP * sizeof(int), stream);
  k_scatter<<<NS / 256, 256, 0, stream>>>(idxs, cursors, bucket);
  dim3 grid(GX, KEXP);
  k_mlp<<<grid, 256, 0, stream>>>(cursors, bucket, pos, view, feat,
                                  W0, b0, W1, b1, W2, b2, out);
}

// Round 6
// 102.667 us; speedup vs baseline: 1.0514x; 1.0128x over previous
//
#include <hip/hip_runtime.h>
#include <hip/hip_bf16.h>

// Problem constants
#define NS    65536
#define KEXP  8
#define WID   64
#define DOUT  32
#define DIN   74
#define TM    64     // samples per tile
#define XS    104    // X row stride (u16), mult of 8 -> 16B-aligned b128 frags
#define HS    72     // H / W1t / W2t row stride (u16)
#define GX    64     // blocks per expert in MLP kernel
#define NB    256    // scatter blocks (NS/256)

typedef __attribute__((ext_vector_type(8))) short short8;
typedef __attribute__((ext_vector_type(4))) float floatx4;

// f32 -> bf16 round-to-nearest-even.
__device__ __forceinline__ unsigned short f2b(float f) {
  unsigned u = __builtin_bit_cast(unsigned, f);
  u = u + 0x7FFFu + ((u >> 16) & 1u);
  return (unsigned short)(u >> 16);
}

// d_ws layout:
//   bytes [0 .. 1MB)       : bucket, u16[KEXP][NB][256]  (block-sliced, no init needed)
//   bytes [1MB .. 1MB+8KB) : hist, int[NB][KEXP]         (plain stores, no init needed)
// Design is memset-free and global-atomic-free: every ws word we read was
// written earlier in the same launch (scatter -> mlp graph edge).

__global__ __launch_bounds__(256) void k_scatter(const int* __restrict__ idxs,
                                                 unsigned short* __restrict__ bucket,
                                                 int* __restrict__ hist) {
  __shared__ int lc[KEXP];
  const int tid = threadIdx.x;
  const int b = blockIdx.x;
  if (tid < KEXP) lc[tid] = 0;
  __syncthreads();
  const int gid = b * 256 + tid;
  const int e = idxs[gid];
  const int rank = atomicAdd(&lc[e], 1);          // LDS atomic
  bucket[(e << 16) + (b << 8) + rank] = (unsigned short)gid;
  __syncthreads();
  if (tid < KEXP) hist[b * KEXP + tid] = lc[tid];
}

__global__ __launch_bounds__(256) void k_mlp(
    const int* __restrict__ hist,
    const unsigned short* __restrict__ bucket,
    const float* __restrict__ pos,
    const float* __restrict__ view,
    const float* __restrict__ feat,
    const float* __restrict__ W0,
    const float* __restrict__ B0,
    const float* __restrict__ W1,
    const float* __restrict__ B1,
    const float* __restrict__ W2,
    const float* __restrict__ B2,
    float* __restrict__ out)
{
  const int e = blockIdx.y;
  const int tid = threadIdx.x;

  __shared__ __align__(16) unsigned short Xs[TM * XS];
  __shared__ __align__(16) unsigned short W0t[WID * XS];
  __shared__ __align__(16) unsigned short W1t[WID * HS];
  __shared__ __align__(16) unsigned short W2t[DOUT * HS];
  __shared__ __align__(16) unsigned short Hs[TM * HS];
  __shared__ float sb0[WID];
  __shared__ float sb1[WID];
  __shared__ float sb2[DOUT];
  __shared__ int sid[TM];
  __shared__ unsigned cn[NB];    // per-source-block count for expert e
  __shared__ unsigned pref[NB];  // inclusive prefix of cn

  // ---- prefix-scan the 256 per-block counts for this expert ----
  cn[tid] = (unsigned)hist[tid * KEXP + e];
  pref[tid] = cn[tid];
  __syncthreads();
  #pragma unroll
  for (int st = 1; st < NB; st <<= 1) {
    const unsigned v = (tid >= st) ? pref[tid - st] : 0u;
    __syncthreads();
    pref[tid] += v;
    __syncthreads();
  }
  const int segCnt = (int)pref[NB - 1];
  if ((int)blockIdx.x * TM >= segCnt) return;

  // Zero Xs k-padding region (cols 74..95 read by MFMA) and W0t padding.
  for (int i = tid; i < TM * XS; i += 256) Xs[i] = 0;
  for (int i = tid; i < WID * XS; i += 256) W0t[i] = 0;
  __syncthreads();

  // ---- stage weights transposed, Wt[o][i] = W[i][o], 4 i per thread ----
  {
    const float* g0 = W0 + (size_t)e * DIN * WID;
    for (int g = tid; g < 19 * WID; g += 256) {        // ceil(74/4)=19 blocks
      const int o = g & 63, i4 = g >> 6, ib = i4 * 4;
      unsigned v0 = 0, v1 = 0;
      #pragma unroll
      for (int j = 0; j < 4; ++j) {
        const int i = ib + j;
        unsigned short w = (i < DIN) ? f2b(g0[i * WID + o]) : (unsigned short)0;
        if (j < 2) v0 |= (unsigned)w << (16 * j);
        else       v1 |= (unsigned)w << (16 * (j - 2));
      }
      *(uint2*)&W0t[o * XS + ib] = make_uint2(v0, v1);
    }
    const float* g1 = W1 + (size_t)e * WID * WID;
    for (int g = tid; g < 16 * WID; g += 256) {
      const int o = g & 63, i4 = g >> 6, ib = i4 * 4;
      unsigned v0, v1;
      v0 = (unsigned)f2b(g1[(ib + 0) * WID + o]) | ((unsigned)f2b(g1[(ib + 1) * WID + o]) << 16);
      v1 = (unsigned)f2b(g1[(ib + 2) * WID + o]) | ((unsigned)f2b(g1[(ib + 3) * WID + o]) << 16);
      *(uint2*)&W1t[o * HS + ib] = make_uint2(v0, v1);
    }
    const float* g2 = W2 + (size_t)e * WID * DOUT;
    for (int g = tid; g < 16 * DOUT; g += 256) {
      const int o = g & 31, i4 = g >> 5, ib = i4 * 4;
      unsigned v0, v1;
      v0 = (unsigned)f2b(g2[(ib + 0) * DOUT + o]) | ((unsigned)f2b(g2[(ib + 1) * DOUT + o]) << 16);
      v1 = (unsigned)f2b(g2[(ib + 2) * DOUT + o]) | ((unsigned)f2b(g2[(ib + 3) * DOUT + o]) << 16);
      *(uint2*)&W2t[o * HS + ib] = make_uint2(v0, v1);
    }
    if (tid < WID) {
      sb0[tid] = B0[e * WID + tid];
      sb1[tid] = B1[e * WID + tid];
    } else if (tid < WID + DOUT) {
      const int t = tid - WID;
      sb2[t] = B2[e * DOUT + t];
    }
  }
  __syncthreads();

  const int lane = tid & 63;
  const int wv = tid >> 6;
  const int quad = lane >> 4;
  const int r16 = lane & 15;
  const int rb = wv * 16;

  for (int tile = blockIdx.x; tile * TM < segCnt; tile += GX) {
    const int t0 = tile * TM;
    const int rows = min(TM, segCnt - t0);

    __syncthreads();   // protect Xs/sid rebuild vs previous iteration's readers

    // ---- build X tile: row = lane, 4-way split across waves ----
    const int r = lane;
    if (r < rows) {
      // map sorted position p -> (source block sb_, local rank) -> sample id
      const int p = t0 + r;
      int lo = 0, hi = NB - 1;
      #pragma unroll
      for (int it = 0; it < 8; ++it) {
        const int mid = (lo + hi) >> 1;
        if (pref[mid] > (unsigned)p) hi = mid; else lo = mid + 1;
      }
      const int sb_ = lo;
      const int local = p - (int)(pref[sb_] - cn[sb_]);
      const int s = (int)bucket[(e << 16) + (sb_ << 8) + local];
      unsigned short* xr = &Xs[r * XS];
      if (wv == 0) {
        sid[r] = s;
        const float4* fs = (const float4*)(feat + (size_t)s * DOUT);
        #pragma unroll
        for (int q = 0; q < 4; ++q) {
          float4 f = fs[q];
          xr[q * 4 + 0] = f2b(f.x);
          xr[q * 4 + 1] = f2b(f.y);
          xr[q * 4 + 2] = f2b(f.z);
          xr[q * 4 + 3] = f2b(f.w);
        }
      } else if (wv == 1) {
        const float4* fs = (const float4*)(feat + (size_t)s * DOUT);
        #pragma unroll
        for (int q = 4; q < 8; ++q) {
          float4 f = fs[q];
          xr[q * 4 + 0] = f2b(f.x);
          xr[q * 4 + 1] = f2b(f.y);
          xr[q * 4 + 2] = f2b(f.z);
          xr[q * 4 + 3] = f2b(f.w);
        }
      } else if (wv == 2) {
        // posenc(positions, deg=2): cols 32..46
        float p3[3];
        p3[0] = pos[s * 3 + 0];
        p3[1] = pos[s * 3 + 1];
        p3[2] = pos[s * 3 + 2];
        #pragma unroll
        for (int d = 0; d < 3; ++d) xr[32 + d] = f2b(p3[d]);
        #pragma unroll
        for (int si = 0; si < 2; ++si) {
          const float sc = (float)(1 << si);
          #pragma unroll
          for (int d = 0; d < 3; ++d) {
            const float a = p3[d] * sc;
            xr[35 + si * 3 + d] = f2b(__sinf(a));
            xr[41 + si * 3 + d] = f2b(__cosf(a));
          }
        }
      } else {
        // posenc(viewdirs, deg=4): cols 47..73
        float v3[3];
        v3[0] = view[s * 3 + 0];
        v3[1] = view[s * 3 + 1];
        v3[2] = view[s * 3 + 2];
        #pragma unroll
        for (int d = 0; d < 3; ++d) xr[47 + d] = f2b(v3[d]);
        #pragma unroll
        for (int si = 0; si < 4; ++si) {
          const float sc = (float)(1 << si);
          #pragma unroll
          for (int d = 0; d < 3; ++d) {
            const float a = v3[d] * sc;
            xr[50 + si * 3 + d] = f2b(__sinf(a));
            xr[62 + si * 3 + d] = f2b(__cosf(a));
          }
        }
      }
    }
    __syncthreads();

    // ---- layer 0: [64 x 96] @ [96 x 64] -> Hs (relu). Hs rows wave-private. ----
    {
      const short8 a0 = *(const short8*)&Xs[(rb + r16) * XS + 0 + quad * 8];
      const short8 a1 = *(const short8*)&Xs[(rb + r16) * XS + 32 + quad * 8];
      const short8 a2 = *(const short8*)&Xs[(rb + r16) * XS + 64 + quad * 8];
      #pragma unroll
      for (int c = 0; c < 4; ++c) {
        const int n0 = c * 16;
        floatx4 acc = {0.f, 0.f, 0.f, 0.f};
        acc = __builtin_amdgcn_mfma_f32_16x16x32_bf16(
            a0, *(const short8*)&W0t[(n0 + r16) * XS + 0 + quad * 8], acc, 0, 0, 0);
        acc = __builtin_amdgcn_mfma_f32_16x16x32_bf16(
            a1, *(const short8*)&W0t[(n0 + r16) * XS + 32 + quad * 8], acc, 0, 0, 0);
        acc = __builtin_amdgcn_mfma_f32_16x16x32_bf16(
            a2, *(const short8*)&W0t[(n0 + r16) * XS + 64 + quad * 8], acc, 0, 0, 0);
        const float bias = sb0[n0 + r16];
        #pragma unroll
        for (int g = 0; g < 4; ++g) {
          const float vv = fmaxf(acc[g] + bias, 0.f);
          Hs[(rb + quad * 4 + g) * HS + n0 + r16] = f2b(vv);
        }
      }
    }

    // ---- layer 1: [64 x 64] @ [64 x 64] -> Hs (relu, wave-private rows) ----
    {
      const short8 h0 = *(const short8*)&Hs[(rb + r16) * HS + 0 + quad * 8];
      const short8 h1 = *(const short8*)&Hs[(rb + r16) * HS + 32 + quad * 8];
      #pragma unroll
      for (int c = 0; c < 4; ++c) {
        const int n0 = c * 16;
        floatx4 acc = {0.f, 0.f, 0.f, 0.f};
        acc = __builtin_amdgcn_mfma_f32_16x16x32_bf16(
            h0, *(const short8*)&W1t[(n0 + r16) * HS + 0 + quad * 8], acc, 0, 0, 0);
        acc = __builtin_amdgcn_mfma_f32_16x16x32_bf16(
            h1, *(const short8*)&W1t[(n0 + r16) * HS + 32 + quad * 8], acc, 0, 0, 0);
        const float bias = sb1[n0 + r16];
        #pragma unroll
        for (int g = 0; g < 4; ++g) {
          const float vv = fmaxf(acc[g] + bias, 0.f);
          Hs[(rb + quad * 4 + g) * HS + n0 + r16] = f2b(vv);
        }
      }
    }

    // ---- layer 2: [64 x 64] @ [64 x 32] -> direct f32 global stores ----
    {
      const short8 q0 = *(const short8*)&Hs[(rb + r16) * HS + 0 + quad * 8];
      const short8 q1 = *(const short8*)&Hs[(rb + r16) * HS + 32 + quad * 8];
      #pragma unroll
      for (int c = 0; c < 2; ++c) {
        const int n0 = c * 16;
        floatx4 acc = {0.f, 0.f, 0.f, 0.f};
        acc = __builtin_amdgcn_mfma_f32_16x16x32_bf16(
            q0, *(const short8*)&W2t[(n0 + r16) * HS + 0 + quad * 8], acc, 0, 0, 0);
        acc = __builtin_amdgcn_mfma_f32_16x16x32_bf16(
            q1, *(const short8*)&W2t[(n0 + r16) * HS + 32 + quad * 8], acc, 0, 0, 0);
        const float bias = sb2[n0 + r16];
        const int col = n0 + r16;
        #pragma unroll
        for (int g = 0; g < 4; ++g) {
          const int row = rb + quad * 4 + g;
          if (row < rows) {
            out[(size_t)sid[row] * DOUT + col] = acc[g] + bias;
          }
        }
      }
    }
  }
}

extern "C" void kernel_launch(void* const* d_in, const int* in_sizes, int n_in,
                              void* d_out, int out_size, void* d_ws, size_t ws_size,
                              hipStream_t stream) {
  const int* idxs        = (const int*)d_in[0];
  const float* pos       = (const float*)d_in[1];
  const float* view      = (const float*)d_in[2];
  const float* feat      = (const float*)d_in[3];
  const float* W0        = (const float*)d_in[4];
  const float* b0        = (const float*)d_in[5];
  const float* W1        = (const float*)d_in[6];
  const float* b1        = (const float*)d_in[7];
  const float* W2        = (const float*)d_in[8];
  const float* b2        = (const float*)d_in[9];
  float* out             = (float*)d_out;
  unsigned short* bucket = (unsigned short*)d_ws;
  int* hist              = (int*)((char*)d_ws + (size_t)KEXP * NB * 256 * 2);

  k_scatter<<<NB, 256, 0, stream>>>(idxs, bucket, hist);
  dim3 grid(GX, KEXP);
  k_mlp<<<grid, 256, 0, stream>>>(hist, bucket, pos, view, feat,
                                  W0, b0, W1, b1, W2, b2, out);
}

// Round 7
// 101.028 us; speedup vs baseline: 1.0685x; 1.0162x over previous
//
#include <hip/hip_runtime.h>
#include <hip/hip_bf16.h>

// Problem constants
#define NS    65536
#define KEXP  8
#define WID   64
#define DOUT  32
#define DIN   74
#define TM    64     // samples per tile
#define XS    104    // X row stride (u16), mult of 8 -> 16B-aligned b128 frags
#define HS    72     // H / W1t / W2t row stride (u16)
#define GX    64     // blocks per expert in MLP kernel
#define NB    64     // scatter blocks (NS/1024)

typedef __attribute__((ext_vector_type(8))) short short8;
typedef __attribute__((ext_vector_type(4))) float floatx4;

// f32 -> bf16 round-to-nearest-even.
__device__ __forceinline__ unsigned short f2b(float f) {
  unsigned u = __builtin_bit_cast(unsigned, f);
  u = u + 0x7FFFu + ((u >> 16) & 1u);
  return (unsigned short)(u >> 16);
}

// d_ws layout:
//   bytes [0 .. 1MB)       : bucket, u16[KEXP][NB][1024] (block-sliced, no init needed)
//   bytes [1MB .. 1MB+2KB) : hist, int[NB][KEXP]         (plain stores, no init needed)
// Memset-free and global-atomic-free: every ws word read was written earlier
// in the same launch (scatter -> mlp graph edge).

__global__ __launch_bounds__(1024) void k_scatter(const int* __restrict__ idxs,
                                                  unsigned short* __restrict__ bucket,
                                                  int* __restrict__ hist) {
  __shared__ int lc[KEXP];
  const int tid = threadIdx.x;
  const int b = blockIdx.x;
  if (tid < KEXP) lc[tid] = 0;
  __syncthreads();
  const int gid = b * 1024 + tid;
  const int e = idxs[gid];
  const int rank = atomicAdd(&lc[e], 1);          // LDS atomic
  bucket[(e << 16) + (b << 10) + rank] = (unsigned short)gid;
  __syncthreads();
  if (tid < KEXP) hist[b * KEXP + tid] = lc[tid];
}

__global__ __launch_bounds__(256) void k_mlp(
    const int* __restrict__ hist,
    const unsigned short* __restrict__ bucket,
    const float* __restrict__ pos,
    const float* __restrict__ view,
    const float* __restrict__ feat,
    const float* __restrict__ W0,
    const float* __restrict__ B0,
    const float* __restrict__ W1,
    const float* __restrict__ B1,
    const float* __restrict__ W2,
    const float* __restrict__ B2,
    float* __restrict__ out)
{
  const int e = blockIdx.y;
  const int tid = threadIdx.x;

  __shared__ __align__(16) unsigned short Xs[TM * XS];
  __shared__ __align__(16) unsigned short W0t[WID * XS];
  __shared__ __align__(16) unsigned short W1t[WID * HS];
  __shared__ __align__(16) unsigned short W2t[DOUT * HS];
  __shared__ __align__(16) unsigned short Hs[TM * HS];
  __shared__ float sb0[WID];
  __shared__ float sb1[WID];
  __shared__ float sb2[DOUT];
  __shared__ int sid[TM];
  __shared__ unsigned cns[NB];   // per-source-block count for expert e
  __shared__ unsigned pref[NB];  // inclusive prefix of cns

  // ---- wave 0: load 64 per-block counts, shfl inclusive scan (no barriers);
  //      all threads meanwhile zero Xs k-padding + W0t padding. One barrier. ----
  if (tid < NB) {
    const unsigned c = (unsigned)hist[tid * KEXP + e];
    unsigned p = c;
    #pragma unroll
    for (int st = 1; st < NB; st <<= 1) {
      const unsigned v = __shfl_up(p, st, 64);
      if ((tid & 63) >= st) p += v;
    }
    cns[tid] = c;
    pref[tid] = p;
  }
  for (int i = tid; i < TM * XS; i += 256) Xs[i] = 0;
  for (int i = tid; i < WID * XS; i += 256) W0t[i] = 0;
  __syncthreads();

  const int segCnt = (int)pref[NB - 1];
  if ((int)blockIdx.x * TM >= segCnt) return;

  // ---- stage weights transposed, Wt[o][i] = W[i][o], 4 i per thread ----
  {
    const float* g0 = W0 + (size_t)e * DIN * WID;
    for (int g = tid; g < 19 * WID; g += 256) {        // ceil(74/4)=19 blocks
      const int o = g & 63, i4 = g >> 6, ib = i4 * 4;
      unsigned v0 = 0, v1 = 0;
      #pragma unroll
      for (int j = 0; j < 4; ++j) {
        const int i = ib + j;
        unsigned short w = (i < DIN) ? f2b(g0[i * WID + o]) : (unsigned short)0;
        if (j < 2) v0 |= (unsigned)w << (16 * j);
        else       v1 |= (unsigned)w << (16 * (j - 2));
      }
      *(uint2*)&W0t[o * XS + ib] = make_uint2(v0, v1);
    }
    const float* g1 = W1 + (size_t)e * WID * WID;
    for (int g = tid; g < 16 * WID; g += 256) {
      const int o = g & 63, i4 = g >> 6, ib = i4 * 4;
      unsigned v0, v1;
      v0 = (unsigned)f2b(g1[(ib + 0) * WID + o]) | ((unsigned)f2b(g1[(ib + 1) * WID + o]) << 16);
      v1 = (unsigned)f2b(g1[(ib + 2) * WID + o]) | ((unsigned)f2b(g1[(ib + 3) * WID + o]) << 16);
      *(uint2*)&W1t[o * HS + ib] = make_uint2(v0, v1);
    }
    const float* g2 = W2 + (size_t)e * WID * DOUT;
    for (int g = tid; g < 16 * DOUT; g += 256) {
      const int o = g & 31, i4 = g >> 5, ib = i4 * 4;
      unsigned v0, v1;
      v0 = (unsigned)f2b(g2[(ib + 0) * DOUT + o]) | ((unsigned)f2b(g2[(ib + 1) * DOUT + o]) << 16);
      v1 = (unsigned)f2b(g2[(ib + 2) * DOUT + o]) | ((unsigned)f2b(g2[(ib + 3) * DOUT + o]) << 16);
      *(uint2*)&W2t[o * HS + ib] = make_uint2(v0, v1);
    }
    if (tid < WID) {
      sb0[tid] = B0[e * WID + tid];
      sb1[tid] = B1[e * WID + tid];
    } else if (tid < WID + DOUT) {
      const int t = tid - WID;
      sb2[t] = B2[e * DOUT + t];
    }
  }
  __syncthreads();

  const int lane = tid & 63;
  const int wv = tid >> 6;
  const int quad = lane >> 4;
  const int r16 = lane & 15;
  const int rb = wv * 16;

  for (int tile = blockIdx.x; tile * TM < segCnt; tile += GX) {
    const int t0 = tile * TM;
    const int rows = min(TM, segCnt - t0);

    __syncthreads();   // protect Xs/sid rebuild vs previous iteration's readers

    // ---- build X tile: row = lane, 4-way split across waves ----
    const int r = lane;
    if (r < rows) {
      // map sorted position p -> (source block sb_, local rank) -> sample id
      const int p = t0 + r;
      int lo = 0, hi = NB - 1;
      #pragma unroll
      for (int it = 0; it < 6; ++it) {
        const int mid = (lo + hi) >> 1;
        if (pref[mid] > (unsigned)p) hi = mid; else lo = mid + 1;
      }
      const int sb_ = lo;
      const int local = p - (int)(pref[sb_] - cns[sb_]);
      const int s = (int)bucket[(e << 16) + (sb_ << 10) + local];
      unsigned short* xr = &Xs[r * XS];
      if (wv == 0) {
        sid[r] = s;
        const float4* fs = (const float4*)(feat + (size_t)s * DOUT);
        #pragma unroll
        for (int q = 0; q < 4; ++q) {
          float4 f = fs[q];
          xr[q * 4 + 0] = f2b(f.x);
          xr[q * 4 + 1] = f2b(f.y);
          xr[q * 4 + 2] = f2b(f.z);
          xr[q * 4 + 3] = f2b(f.w);
        }
      } else if (wv == 1) {
        const float4* fs = (const float4*)(feat + (size_t)s * DOUT);
        #pragma unroll
        for (int q = 4; q < 8; ++q) {
          float4 f = fs[q];
          xr[q * 4 + 0] = f2b(f.x);
          xr[q * 4 + 1] = f2b(f.y);
          xr[q * 4 + 2] = f2b(f.z);
          xr[q * 4 + 3] = f2b(f.w);
        }
      } else if (wv == 2) {
        // posenc(positions, deg=2): cols 32..46
        float p3[3];
        p3[0] = pos[s * 3 + 0];
        p3[1] = pos[s * 3 + 1];
        p3[2] = pos[s * 3 + 2];
        #pragma unroll
        for (int d = 0; d < 3; ++d) xr[32 + d] = f2b(p3[d]);
        #pragma unroll
        for (int si = 0; si < 2; ++si) {
          const float sc = (float)(1 << si);
          #pragma unroll
          for (int d = 0; d < 3; ++d) {
            const float a = p3[d] * sc;
            xr[35 + si * 3 + d] = f2b(__sinf(a));
            xr[41 + si * 3 + d] = f2b(__cosf(a));
          }
        }
      } else {
        // posenc(viewdirs, deg=4): cols 47..73
        float v3[3];
        v3[0] = view[s * 3 + 0];
        v3[1] = view[s * 3 + 1];
        v3[2] = view[s * 3 + 2];
        #pragma unroll
        for (int d = 0; d < 3; ++d) xr[47 + d] = f2b(v3[d]);
        #pragma unroll
        for (int si = 0; si < 4; ++si) {
          const float sc = (float)(1 << si);
          #pragma unroll
          for (int d = 0; d < 3; ++d) {
            const float a = v3[d] * sc;
            xr[50 + si * 3 + d] = f2b(__sinf(a));
            xr[62 + si * 3 + d] = f2b(__cosf(a));
          }
        }
      }
    }
    __syncthreads();

    // ---- layer 0: [64 x 96] @ [96 x 64] -> Hs (relu). Hs rows wave-private. ----
    {
      const short8 a0 = *(const short8*)&Xs[(rb + r16) * XS + 0 + quad * 8];
      const short8 a1 = *(const short8*)&Xs[(rb + r16) * XS + 32 + quad * 8];
      const short8 a2 = *(const short8*)&Xs[(rb + r16) * XS + 64 + quad * 8];
      #pragma unroll
      for (int c = 0; c < 4; ++c) {
        const int n0 = c * 16;
        floatx4 acc = {0.f, 0.f, 0.f, 0.f};
        acc = __builtin_amdgcn_mfma_f32_16x16x32_bf16(
            a0, *(const short8*)&W0t[(n0 + r16) * XS + 0 + quad * 8], acc, 0, 0, 0);
        acc = __builtin_amdgcn_mfma_f32_16x16x32_bf16(
            a1, *(const short8*)&W0t[(n0 + r16) * XS + 32 + quad * 8], acc, 0, 0, 0);
        acc = __builtin_amdgcn_mfma_f32_16x16x32_bf16(
            a2, *(const short8*)&W0t[(n0 + r16) * XS + 64 + quad * 8], acc, 0, 0, 0);
        const float bias = sb0[n0 + r16];
        #pragma unroll
        for (int g = 0; g < 4; ++g) {
          const float vv = fmaxf(acc[g] + bias, 0.f);
          Hs[(rb + quad * 4 + g) * HS + n0 + r16] = f2b(vv);
        }
      }
    }

    // ---- layer 1: [64 x 64] @ [64 x 64] -> Hs (relu, wave-private rows) ----
    {
      const short8 h0 = *(const short8*)&Hs[(rb + r16) * HS + 0 + quad * 8];
      const short8 h1 = *(const short8*)&Hs[(rb + r16) * HS + 32 + quad * 8];
      #pragma unroll
      for (int c = 0; c < 4; ++c) {
        const int n0 = c * 16;
        floatx4 acc = {0.f, 0.f, 0.f, 0.f};
        acc = __builtin_amdgcn_mfma_f32_16x16x32_bf16(
            h0, *(const short8*)&W1t[(n0 + r16) * HS + 0 + quad * 8], acc, 0, 0, 0);
        acc = __builtin_amdgcn_mfma_f32_16x16x32_bf16(
            h1, *(const short8*)&W1t[(n0 + r16) * HS + 32 + quad * 8], acc, 0, 0, 0);
        const float bias = sb1[n0 + r16];
        #pragma unroll
        for (int g = 0; g < 4; ++g) {
          const float vv = fmaxf(acc[g] + bias, 0.f);
          Hs[(rb + quad * 4 + g) * HS + n0 + r16] = f2b(vv);
        }
      }
    }

    // ---- layer 2: [64 x 64] @ [64 x 32] -> direct f32 global stores ----
    {
      const short8 q0 = *(const short8*)&Hs[(rb + r16) * HS + 0 + quad * 8];
      const short8 q1 = *(const short8*)&Hs[(rb + r16) * HS + 32 + quad * 8];
      #pragma unroll
      for (int c = 0; c < 2; ++c) {
        const int n0 = c * 16;
        floatx4 acc = {0.f, 0.f, 0.f, 0.f};
        acc = __builtin_amdgcn_mfma_f32_16x16x32_bf16(
            q0, *(const short8*)&W2t[(n0 + r16) * HS + 0 + quad * 8], acc, 0, 0, 0);
        acc = __builtin_amdgcn_mfma_f32_16x16x32_bf16(
            q1, *(const short8*)&W2t[(n0 + r16) * HS + 32 + quad * 8], acc, 0, 0, 0);
        const float bias = sb2[n0 + r16];
        const int col = n0 + r16;
        #pragma unroll
        for (int g = 0; g < 4; ++g) {
          const int row = rb + quad * 4 + g;
          if (row < rows) {
            out[(size_t)sid[row] * DOUT + col] = acc[g] + bias;
          }
        }
      }
    }
  }
}

extern "C" void kernel_launch(void* const* d_in, const int* in_sizes, int n_in,
                              void* d_out, int out_size, void* d_ws, size_t ws_size,
                              hipStream_t stream) {
  const int* idxs        = (const int*)d_in[0];
  const float* pos       = (const float*)d_in[1];
  const float* view      = (const float*)d_in[2];
  const float* feat      = (const float*)d_in[3];
  const float* W0        = (const float*)d_in[4];
  const float* b0        = (const float*)d_in[5];
  const float* W1        = (const float*)d_in[6];
  const float* b1        = (const float*)d_in[7];
  const float* W2        = (const float*)d_in[8];
  const float* b2        = (const float*)d_in[9];
  float* out             = (float*)d_out;
  unsigned short* bucket = (unsigned short*)d_ws;
  int* hist              = (int*)((char*)d_ws + (size_t)KEXP * NB * 1024 * 2);

  k_scatter<<<NB, 1024, 0, stream>>>(idxs, bucket, hist);
  dim3 grid(GX, KEXP);
  k_mlp<<<grid, 256, 0, stream>>>(hist, bucket, pos, view, feat,
                                  W0, b0, W1, b1, W2, b2, out);
}